// Round 5
// baseline (368.924 us; speedup 1.0000x reference)
//
#include <hip/hip_runtime.h>
#include <hip/hip_bf16.h>
#include <cstdint>

#define NEG_SLOPE 0.2f
#define SCAN_ELEMS 1024   // elements per scan block (256 thr x 4)
#define BUCKET_SHIFT 9    // 512 nodes per bucket
#define CHUNK 8192        // edges per bucketing block

typedef __attribute__((ext_vector_type(4))) int            i32x4;
typedef __attribute__((ext_vector_type(4))) float          f32x4;
typedef __attribute__((ext_vector_type(8))) unsigned short u16x8;
typedef __attribute__((ext_vector_type(4))) unsigned short u16x4;

__device__ inline unsigned short f2bf(float f) {  // round-to-nearest-even
    unsigned xi = __float_as_uint(f);
    unsigned r = xi + 0x7fffu + ((xi >> 16) & 1u);
    return (unsigned short)(r >> 16);
}
__device__ inline float bflo(unsigned g) { return __uint_as_float(g << 16); }
__device__ inline float bfhi(unsigned g) { return __uint_as_float(g & 0xffff0000u); }

__device__ inline int get_ei(const int* ei, int is64, long idx) {
    return is64 ? ei[2 * idx] : ei[(int)idx];
}

// In-block int64 detection: OR of odd words of the first 2048 src entries
// (zero for little-endian int64 ids < 2^31; random node ids for int32).
__device__ inline int detect_is64(const int* __restrict__ ei, int tid) {
    __shared__ int dred[4];
    int v = 0;
    for (int i = tid; i < 2048; i += 256) v |= ei[2 * i + 1];
#pragma unroll
    for (int off = 32; off; off >>= 1) v |= __shfl_xor(v, off);
    if ((tid & 63) == 0) dred[tid >> 6] = v;
    __syncthreads();
    int r = dred[0] | dred[1] | dred[2] | dred[3];
    __syncthreads();   // protect dred reuse safety across callers
    return (r == 0) ? 1 : 0;
}

// ---------------------------------------------------------------------------
// Counting-sort CSR build.
// ---------------------------------------------------------------------------
__global__ __launch_bounds__(256) void p1_hist(const int* __restrict__ ei,
                                               int* __restrict__ HH,
                                               int E, int n, int nblk) {
    __shared__ int cnt[256];
    int tid = threadIdx.x;
    int is64 = detect_is64(ei, tid);
    int nbuk = (n + (1 << BUCKET_SHIFT) - 1) >> BUCKET_SHIFT;  // <=256
    for (int b = tid; b < nbuk; b += 256) cnt[b] = 0;
    __syncthreads();
    int total = E + n;
    int beg = blockIdx.x * CHUNK;
    int end = beg + CHUNK; if (end > total) end = total;
    for (int i = beg + tid; i < end; i += 256) {
        int d = (i < E) ? get_ei(ei, is64, (long)E + i) : (i - E);
        atomicAdd(&cnt[d >> BUCKET_SHIFT], 1);
    }
    __syncthreads();
    for (int b = tid; b < nbuk; b += 256) HH[b * nblk + blockIdx.x] = cnt[b];
}

__global__ __launch_bounds__(256) void scan1_kernel(const int* __restrict__ src,
                                                    int* __restrict__ bsums, int n) {
    int t = threadIdx.x;
    int i0 = blockIdx.x * SCAN_ELEMS + 4 * t;
    int4 v = make_int4(0, 0, 0, 0);
    if (i0 + 3 < n) v = *(const int4*)(src + i0);
    else {
        if (i0 + 0 < n) v.x = src[i0 + 0];
        if (i0 + 1 < n) v.y = src[i0 + 1];
        if (i0 + 2 < n) v.z = src[i0 + 2];
        if (i0 + 3 < n) v.w = src[i0 + 3];
    }
    int s = v.x + v.y + v.z + v.w;
#pragma unroll
    for (int off = 32; off; off >>= 1) s += __shfl_down(s, off);
    __shared__ int ws[4];
    if ((t & 63) == 0) ws[t >> 6] = s;
    __syncthreads();
    if (t == 0) bsums[blockIdx.x] = ws[0] + ws[1] + ws[2] + ws[3];
}

__global__ __launch_bounds__(256) void scan3g_kernel(const int* __restrict__ src,
                                                     const int* __restrict__ bsums,
                                                     int* __restrict__ out, int n, int nb) {
    int b = blockIdx.x;
    int t = threadIdx.x;
    __shared__ int sb[256];
    int bv = (t < nb) ? bsums[t] : 0;
    sb[t] = bv;
    __syncthreads();
    for (int off = 1; off < 256; off <<= 1) {
        int u = (t >= off) ? sb[t - off] : 0;
        __syncthreads();
        sb[t] += u;
        __syncthreads();
    }
    int blockbase = (b == 0) ? 0 : sb[b - 1];

    int i0 = b * SCAN_ELEMS + 4 * t;
    int4 v = make_int4(0, 0, 0, 0);
    if (i0 + 3 < n) v = *(const int4*)(src + i0);
    else {
        if (i0 + 0 < n) v.x = src[i0 + 0];
        if (i0 + 1 < n) v.y = src[i0 + 1];
        if (i0 + 2 < n) v.z = src[i0 + 2];
        if (i0 + 3 < n) v.w = src[i0 + 3];
    }
    int s0 = v.x, s1 = s0 + v.y, s2 = s1 + v.z, s3 = s2 + v.w;
    __shared__ int sh[256];
    sh[t] = s3;
    __syncthreads();
    for (int off = 1; off < 256; off <<= 1) {
        int u = (t >= off) ? sh[t - off] : 0;
        __syncthreads();
        sh[t] += u;
        __syncthreads();
    }
    int base = blockbase + sh[t] - s3;
    if (i0 + 0 < n) out[i0 + 0] = base;
    if (i0 + 1 < n) out[i0 + 1] = base + s0;
    if (i0 + 2 < n) out[i0 + 2] = base + s1;
    if (i0 + 3 < n) out[i0 + 3] = base + s2;
}

__global__ __launch_bounds__(256) void p3_scatter(const int* __restrict__ ei,
                                                  const int* __restrict__ scanHH,
                                                  int* __restrict__ sorted,
                                                  int E, int n, int nblk) {
    __shared__ int base[256];
    __shared__ int cur[256];
    int tid = threadIdx.x;
    int is64 = detect_is64(ei, tid);
    int nbuk = (n + (1 << BUCKET_SHIFT) - 1) >> BUCKET_SHIFT;
    for (int b = tid; b < nbuk; b += 256) {
        base[b] = scanHH[b * nblk + blockIdx.x];
        cur[b] = 0;
    }
    __syncthreads();
    int total = E + n;
    int beg = blockIdx.x * CHUNK;
    int end = beg + CHUNK; if (end > total) end = total;
    for (int i = beg + tid; i < end; i += 256) {
        int s, d;
        if (i < E) {
            s = get_ei(ei, is64, i);
            d = get_ei(ei, is64, (long)E + i);
        } else {
            s = d = i - E;
        }
        int b = d >> BUCKET_SHIFT;
        int p = base[b] + atomicAdd(&cur[b], 1);
        sorted[p] = (s << BUCKET_SHIFT) | (d & ((1 << BUCKET_SHIFT) - 1));
    }
}

// p4: one block per bucket -> ptr + csr_sd (int2{src,dst} per edge).
__global__ __launch_bounds__(256) void p4_finalize(const int* __restrict__ scanHH,
                                                   const int* __restrict__ sorted,
                                                   int* __restrict__ ptr,
                                                   int2* __restrict__ csr_sd,
                                                   int n, int nblk, int T) {
    int b = blockIdx.x;
    int nbuk = gridDim.x;
    int tid = threadIdx.x;
    int node0 = b << BUCKET_SHIFT;
    int nn = n - node0; if (nn > (1 << BUCKET_SHIFT)) nn = 1 << BUCKET_SHIFT;
    int beg = scanHH[b * nblk];
    int end = (b + 1 < nbuk) ? scanHH[(b + 1) * nblk] : T;

    __shared__ int cnt[512];
    __shared__ int pair[256];
    __shared__ int exc[512];
    cnt[tid] = 0; cnt[tid + 256] = 0;
    __syncthreads();
    for (int j = beg + tid; j < end; j += 256) {
        int v = sorted[j];
        atomicAdd(&cnt[v & ((1 << BUCKET_SHIFT) - 1)], 1);
    }
    __syncthreads();
    int psum = cnt[2 * tid] + cnt[2 * tid + 1];
    pair[tid] = psum;
    __syncthreads();
    for (int off = 1; off < 256; off <<= 1) {
        int u = (tid >= off) ? pair[tid - off] : 0;
        __syncthreads();
        pair[tid] += u;
        __syncthreads();
    }
    int pexc = pair[tid] - psum;
    exc[2 * tid] = pexc;
    exc[2 * tid + 1] = pexc + cnt[2 * tid];
    __syncthreads();
    for (int i = tid; i < nn; i += 256) ptr[node0 + i] = beg + exc[i];
    if (node0 + nn == n && tid == 0) ptr[n] = T;
    cnt[tid] = exc[tid]; cnt[tid + 256] = exc[tid + 256];
    __syncthreads();
    for (int j = beg + tid; j < end; j += 256) {
        int v = sorted[j];
        int d9 = v & ((1 << BUCKET_SHIFT) - 1);
        int p = beg + atomicAdd(&cnt[d9], 1);
        csr_sd[p] = make_int2((int)(((unsigned)v) >> BUCKET_SHIFT), node0 + d9);
    }
}

// ---------------------------------------------------------------------------
// W pre-pack into MFMA B-fragment order (bf16). Unchanged.
// ---------------------------------------------------------------------------
__global__ __launch_bounds__(256) void pack_w(const float* __restrict__ W1,
                                              const float* __restrict__ W2,
                                              unsigned short* __restrict__ wp1,
                                              unsigned short* __restrict__ wp2) {
    int t = blockIdx.x * 256 + threadIdx.x;
    if (t >= 24 * 64) return;
    int f = t >> 6, l = t & 63;
    int lm = l & 15, lg = l >> 4;
    const float* W = (f < 16) ? W1 : W2;
    unsigned short* wp = (f < 16) ? wp1 : wp2;
    int idx = (f < 16) ? f : (f - 16);
    int kt = idx >> 2, ct = idx & 3;
    union { u16x8 v; unsigned short u[8]; } o;
#pragma unroll
    for (int e = 0; e < 8; ++e)
        o.u[e] = f2bf(W[(size_t)(32 * kt + 8 * lg + e) * 64 + 16 * ct + lm]);
    *(u16x8*)(wp + ((size_t)idx * 64 + l) * 8) = o.v;
}

// ---------------------------------------------------------------------------
// MFMA projection (unchanged from Round 3).
// ---------------------------------------------------------------------------
#define MFMA_BF16(acc, a, b) \
    asm("s_nop 1\n\tv_mfma_f32_16x16x32_bf16 %0, %1, %2, %0" \
        : "+v"(acc) : "v"(a), "v"(b))

template <int KT, bool XBF>   // K = 32*KT
__global__ __launch_bounds__(256) void proj_mfma(const void* __restrict__ xin,
                                                 const unsigned short* __restrict__ Wp,
                                                 const float* __restrict__ att_s,
                                                 const float* __restrict__ att_d,
                                                 unsigned short* __restrict__ h2,
                                                 float* __restrict__ asrc,
                                                 float* __restrict__ adst, int n) {
    constexpr int K = 32 * KT;
    __shared__ alignas(16) unsigned short lb[4][16 * 72];
    int tid = threadIdx.x;
    int wid = tid >> 6, l = tid & 63;
    int lm = l & 15, lg = l >> 4;

    int node0 = blockIdx.x * 64 + wid * 16;
    if (node0 >= n) return;   // wave-uniform; kernel uses no block barriers

    float as_c[4], ad_c[4];
#pragma unroll
    for (int ct = 0; ct < 4; ++ct) {
        as_c[ct] = att_s[16 * ct + lm];
        ad_c[ct] = att_d[16 * ct + lm];
    }

    f32x4 acc[4] = {};

    int arow = node0 + lm;
    bool rowok = arow < n;

#pragma unroll
    for (int kt = 0; kt < KT; ++kt) {
        i32x4 af = {0, 0, 0, 0};
        if (XBF) {
            const unsigned short* xb = (const unsigned short*)xin
                                       + (size_t)arow * K + 32 * kt + 8 * lg;
            if (rowok) af = *(const i32x4*)xb;
        } else {
            const float* xp = (const float*)xin + (size_t)arow * K + 8 * lg + 32 * kt;
            float4 v0 = make_float4(0.f, 0.f, 0.f, 0.f);
            float4 v1 = v0;
            if (rowok) {
                v0 = *(const float4*)(xp);
                v1 = *(const float4*)(xp + 4);
            }
            af[0] = (int)((unsigned)f2bf(v0.x) | ((unsigned)f2bf(v0.y) << 16));
            af[1] = (int)((unsigned)f2bf(v0.z) | ((unsigned)f2bf(v0.w) << 16));
            af[2] = (int)((unsigned)f2bf(v1.x) | ((unsigned)f2bf(v1.y) << 16));
            af[3] = (int)((unsigned)f2bf(v1.z) | ((unsigned)f2bf(v1.w) << 16));
        }
#pragma unroll
        for (int ct = 0; ct < 4; ++ct) {
            i32x4 bf = *(const i32x4*)(Wp + (((kt * 4 + ct) * 64) + l) * 8);
            MFMA_BF16(acc[ct], af, bf);
        }
    }
    // MFMA-write -> VALU-read hazard fence, bound to the accumulators.
    asm volatile("s_nop 7\n\ts_nop 7"
                 : "+v"(acc[0]), "+v"(acc[1]), "+v"(acc[2]), "+v"(acc[3]));

    // attention dots: lane holds cols {16*ct+lm} of rows {4*lg+r}
    float ps[4], pd[4];
#pragma unroll
    for (int r = 0; r < 4; ++r) {
        float s = 0.f, d = 0.f;
#pragma unroll
        for (int ct = 0; ct < 4; ++ct) {
            s = fmaf(acc[ct][r], as_c[ct], s);
            d = fmaf(acc[ct][r], ad_c[ct], d);
        }
        ps[r] = s; pd[r] = d;
    }
#pragma unroll
    for (int off = 1; off < 16; off <<= 1) {
#pragma unroll
        for (int r = 0; r < 4; ++r) {
            ps[r] += __shfl_xor(ps[r], off);
            pd[r] += __shfl_xor(pd[r], off);
        }
    }
    if (lm == 0) {
#pragma unroll
        for (int r = 0; r < 4; ++r) {
            int node = node0 + 4 * lg + r;
            if (node < n) { asrc[node] = ps[r]; adst[node] = pd[r]; }
        }
    }

    // h2 repack via per-wave LDS buffer (wave-local sync only)
    unsigned short* wb = lb[wid];
#pragma unroll
    for (int ct = 0; ct < 4; ++ct)
#pragma unroll
        for (int r = 0; r < 4; ++r)
            wb[(4 * lg + r) * 72 + 16 * ct + lm] = f2bf(acc[ct][r]);
    asm volatile("s_waitcnt lgkmcnt(0)" ::: "memory");
    int ch = l & 7;                       // 16B chunk within a 128B row
#pragma unroll
    for (int p = 0; p < 2; ++p) {
        int rr = (l >> 3) + 8 * p;        // 8 rows per pass, 2 passes = 16 rows
        u16x8 ov = *(const u16x8*)(wb + rr * 72 + 8 * ch);
        int onode = node0 + rr;
        if (onode < n)
            *(u16x8*)(h2 + (size_t)onode * 64 + 8 * ch) = ov;
    }
}

// ---------------------------------------------------------------------------
// Dense edge-parallel softmax weights: sw[e] = {src, exp(leaky(asrc+adst))}.
// 4 edges/thread -> 8 independent L2-hot gathers in flight; fully coalesced
// int2 reads/writes. Removes exp + asrc gather + LDS round-trip from agg.
// ---------------------------------------------------------------------------
__global__ __launch_bounds__(256) void edge_w(const int2* __restrict__ sd,
                                              const float* __restrict__ asrc,
                                              const float* __restrict__ adst,
                                              int2* __restrict__ sw, int T) {
    int i = 4 * (blockIdx.x * 256 + threadIdx.x);
    int stride = 4 * gridDim.x * 256;
    for (; i + 3 < T; i += stride) {
        int2 e[4];
#pragma unroll
        for (int u = 0; u < 4; ++u) e[u] = sd[i + u];
        float s[4], d[4];
#pragma unroll
        for (int u = 0; u < 4; ++u) { s[u] = asrc[e[u].x]; d[u] = adst[e[u].y]; }
#pragma unroll
        for (int u = 0; u < 4; ++u) {
            float v = s[u] + d[u];
            v = (v > 0.f) ? v : NEG_SLOPE * v;
            sw[i + u] = make_int2(e[u].x, __float_as_int(__expf(v)));
        }
    }
    for (int k = i; k < T && k < i + 4; ++k) {
        int2 ev = sd[k];
        float v = asrc[ev.x] + adst[ev.y];
        v = (v > 0.f) ? v : NEG_SLOPE * v;
        sw[k] = make_int2(ev.x, __float_as_int(__expf(v)));
    }
}

// ---------------------------------------------------------------------------
// Aggregation: pure gather-fma. One wave per node; slot = lane>>4 (4 edge
// slots), f = lane&15 (8B feature chunk). Per 16 edges: 4 broadcast int2
// loads of (src,w) (L1-hit: same addr across 16 f-lanes) then 4 INDEPENDENT
// h2 gathers in flight (the MLP Round 3 lost). OOB slots clamp to end-1:
// gather hits the line the valid lanes fetched (no extra traffic), w=0.
// No LDS, no exp, no asrc gather in this kernel.
// ---------------------------------------------------------------------------
template <bool FMEAN>
__global__ __launch_bounds__(256) void agg_kernel(const int* __restrict__ ptr,
                                                  const int2* __restrict__ sw,
                                                  const unsigned short* __restrict__ h2,
                                                  const float* __restrict__ bias,
                                                  unsigned short* __restrict__ outbf,
                                                  float* __restrict__ partials,
                                                  int n, int do_relu) {
    __shared__ float red[256];
    int tid = threadIdx.x;
    int lane = tid & 63, wid = tid >> 6;
    int slot = lane >> 4, f = lane & 15;
    const char* h2b = (const char*)h2;
    unsigned fo = (unsigned)f << 3;            // byte offset of uint2 in row
    float4 bv = *(const float4*)(bias + 4 * f);
    float ms0 = 0.f, ms1 = 0.f, ms2 = 0.f, ms3 = 0.f;

    int gwave = (blockIdx.x * blockDim.x + tid) >> 6;
    int nwaves = (gridDim.x * blockDim.x) >> 6;
    for (int node = gwave; node < n; node += nwaves) {
        int beg = ptr[node], end = ptr[node + 1];
        float a0 = 0.f, a1 = 0.f, a2 = 0.f, a3 = 0.f, wsum = 0.f;
        for (int b = beg; b < end; b += 64) {
            int blen = end - b; if (blen > 64) blen = 64;
            int ni = (blen + 15) >> 4;
            for (int j = 0; j < ni; ++j) {
                int e0 = b + 16 * j + slot;
                int2 swv[4];
#pragma unroll
                for (int u = 0; u < 4; ++u) {
                    int e = e0 + 4 * u;
                    int ec = (e < end) ? e : end - 1;
                    swv[u] = sw[ec];
                }
                uint2 g[4]; float w[4];
#pragma unroll
                for (int u = 0; u < 4; ++u) {
                    w[u] = (e0 + 4 * u < end) ? __int_as_float(swv[u].y) : 0.f;
                    g[u] = *(const uint2*)(h2b + (((unsigned)swv[u].x << 7) + fo));
                }
#pragma unroll
                for (int u = 0; u < 4; ++u) {
                    wsum += w[u];
                    a0 = fmaf(w[u], bflo(g[u].x), a0);
                    a1 = fmaf(w[u], bfhi(g[u].x), a1);
                    a2 = fmaf(w[u], bflo(g[u].y), a2);
                    a3 = fmaf(w[u], bfhi(g[u].y), a3);
                }
            }
        }
        // reduce across the 4 slots (lane bits 4,5); every lane ends with totals
        a0 += __shfl_xor(a0, 16); a0 += __shfl_xor(a0, 32);
        a1 += __shfl_xor(a1, 16); a1 += __shfl_xor(a1, 32);
        a2 += __shfl_xor(a2, 16); a2 += __shfl_xor(a2, 32);
        a3 += __shfl_xor(a3, 16); a3 += __shfl_xor(a3, 32);
        wsum += __shfl_xor(wsum, 16); wsum += __shfl_xor(wsum, 32);
        float inv = 1.f / (wsum + 1e-16f);
        float o0 = a0 * inv + bv.x;
        float o1 = a1 * inv + bv.y;
        float o2 = a2 * inv + bv.z;
        float o3 = a3 * inv + bv.w;
        if (!FMEAN) {
            if (do_relu) {
                o0 = fmaxf(o0, 0.f); o1 = fmaxf(o1, 0.f);
                o2 = fmaxf(o2, 0.f); o3 = fmaxf(o3, 0.f);
            }
            if (slot == 0) {
                u16x4 ov;
                ov[0] = f2bf(o0); ov[1] = f2bf(o1);
                ov[2] = f2bf(o2); ov[3] = f2bf(o3);
                *(u16x4*)(outbf + (size_t)node * 64 + 4 * f) = ov;
            }
        } else {
            if (slot == 0) { ms0 += o0; ms1 += o1; ms2 += o2; ms3 += o3; }
        }
    }
    if (FMEAN) {
        if (slot == 0)
            *(float4*)(red + wid * 64 + 4 * f) = make_float4(ms0, ms1, ms2, ms3);
        __syncthreads();
        if (tid < 64) {
            float t = red[tid] + red[64 + tid] + red[128 + tid] + red[192 + tid];
            partials[(size_t)blockIdx.x * 64 + tid] = t;
        }
    }
}

__global__ __launch_bounds__(256) void reduce_mean(const float* __restrict__ partials,
                                                   float* __restrict__ out,
                                                   int nb, float inv_n) {
    __shared__ float red[256];
    int f = threadIdx.x & 63;
    int w = threadIdx.x >> 6;
    int idx = blockIdx.x * 4 + w;
    int stride = gridDim.x * 4;
    float s = 0.f;
    for (int r = idx; r < nb; r += stride) s += partials[(size_t)r * 64 + f];
    red[threadIdx.x] = s;
    __syncthreads();
    if (w == 0) {
        float t = red[f] + red[64 + f] + red[128 + f] + red[192 + f];
        atomicAdd(&out[f], t * inv_n);
    }
}

extern "C" void kernel_launch(void* const* d_in, const int* in_sizes, int n_in,
                              void* d_out, int out_size, void* d_ws, size_t ws_size,
                              hipStream_t stream) {
    const float* x   = (const float*)d_in[0];
    const int*   ei  = (const int*)d_in[1];
    // d_in[2] = edge_attr (unused by reference, edge_dim=None)
    const float* W1  = (const float*)d_in[3];
    const float* as1 = (const float*)d_in[4];
    const float* ad1 = (const float*)d_in[5];
    const float* b1  = (const float*)d_in[6];
    const float* W2  = (const float*)d_in[7];
    const float* as2 = (const float*)d_in[8];
    const float* ad2 = (const float*)d_in[9];
    const float* b2  = (const float*)d_in[10];
    float* out = (float*)d_out;

    const int N = in_sizes[0] / 128;  // 100000
    const int E = in_sizes[1] / 2;    // 1600000
    const int T = E + N;              // edges incl. self-loops

    const int NBUK = (N + (1 << BUCKET_SHIFT) - 1) >> BUCKET_SHIFT;   // 196
    const int NBLK = (T + CHUNK - 1) / CHUNK;                          // 208
    const int NHH  = NBUK * NBLK;
    const int NBS  = (NHH + SCAN_ELEMS - 1) / SCAN_ELEMS;              // 40
    const int AGRID = (N + 3) / 4;    // one node per wave

    // Workspace carve-up (256B-aligned)
    size_t off = 0;
    char* base = (char*)d_ws;
    auto alloc = [&](size_t bytes) -> void* {
        void* p = base + off;
        off += (bytes + 255) & ~(size_t)255;
        return p;
    };
    int*   ptr     = (int*)alloc(((size_t)N + 1) * 4);
    int*   bsums   = (int*)alloc(256 * 4);
    int*   HH      = (int*)alloc((size_t)NHH * 4);
    int*   scanHH  = (int*)alloc((size_t)NHH * 4);
    int2*  csr_sd  = (int2*)alloc((size_t)T * 8);
    int2*  sw      = (int2*)alloc((size_t)T * 8);
    float* asrc    = (float*)alloc((size_t)N * 4);
    float* adst    = (float*)alloc((size_t)N * 4);
    unsigned short* h2 = (unsigned short*)alloc((size_t)N * 64 * 2);
    // bufB: bf16 h1 (N*64*2) + overlays (sorted T*4, partials AGRID*64*4)
    unsigned short* bufB = (unsigned short*)alloc((size_t)N * 64 * 4);
    unsigned short* wp1 = (unsigned short*)alloc(16 * 64 * 8 * 2);  // 16 KB
    unsigned short* wp2 = (unsigned short*)alloc(8 * 64 * 8 * 2);   //  8 KB
    int*   sorted  = (int*)bufB;      // overlay: dead before agg1 writes bufB
    float* partials = (float*)bufB;   // overlay: bufB dead after proj2 reads it
    (void)ws_size;

    // --- Weight pre-pack for MFMA B-fragments ---
    pack_w<<<6, 256, 0, stream>>>(W1, W2, wp1, wp2);

    // --- CSR build via counting sort (shared by both layers) ---
    p1_hist<<<NBLK, 256, 0, stream>>>(ei, HH, E, N, NBLK);
    scan1_kernel<<<NBS, 256, 0, stream>>>(HH, bsums, NHH);
    scan3g_kernel<<<NBS, 256, 0, stream>>>(HH, bsums, scanHH, NHH, NBS);
    p3_scatter<<<NBLK, 256, 0, stream>>>(ei, scanHH, sorted, E, N, NBLK);
    p4_finalize<<<NBUK, 256, 0, stream>>>(scanHH, sorted, ptr, csr_sd, N, NBLK, T);

    const int PGRID = (N + 63) / 64;
    const int EWGRID = (T + 1023) / 1024;

    // --- Layer 1: MFMA proj -> edge weights -> aggregate (+ReLU, bf16 out) ---
    proj_mfma<4, false><<<PGRID, 256, 0, stream>>>(x, wp1, as1, ad1, h2, asrc, adst, N);
    edge_w<<<EWGRID, 256, 0, stream>>>(csr_sd, asrc, adst, sw, T);
    agg_kernel<false><<<AGRID, 256, 0, stream>>>(ptr, sw, h2, b1, bufB, nullptr, N, 1);

    // --- Layer 2: MFMA proj (bf16 in) -> edge weights -> aggregate + mean ---
    proj_mfma<2, true><<<PGRID, 256, 0, stream>>>(bufB, wp2, as2, ad2, h2, asrc, adst, N);
    edge_w<<<EWGRID, 256, 0, stream>>>(csr_sd, asrc, adst, sw, T);
    agg_kernel<true><<<AGRID, 256, 0, stream>>>(ptr, sw, h2, b2, nullptr, partials, N, 0);
    hipMemsetAsync(out, 0, 64 * 4, stream);
    reduce_mean<<<64, 256, 0, stream>>>(partials, out, AGRID, 1.f / (float)N);
}

// Round 6
// 335.381 us; speedup vs baseline: 1.1000x; 1.1000x over previous
//
#include <hip/hip_runtime.h>
#include <hip/hip_bf16.h>
#include <cstdint>

#define NEG_SLOPE 0.2f
#define SCAN_ELEMS 1024   // elements per scan block (256 thr x 4)
#define BUCKET_SHIFT 9    // 512 nodes per bucket
#define CHUNK 2048        // edges per bucketing block (8192 -> 2048: 831 blocks
                          // instead of 208 -- p1/p3 were occupancy-starved at
                          // 1 block/CU on 208 CUs)

typedef __attribute__((ext_vector_type(4))) int            i32x4;
typedef __attribute__((ext_vector_type(4))) float          f32x4;
typedef __attribute__((ext_vector_type(8))) unsigned short u16x8;
typedef __attribute__((ext_vector_type(4))) unsigned short u16x4;

__device__ inline unsigned short f2bf(float f) {  // round-to-nearest-even
    unsigned xi = __float_as_uint(f);
    unsigned r = xi + 0x7fffu + ((xi >> 16) & 1u);
    return (unsigned short)(r >> 16);
}
__device__ inline float bflo(unsigned g) { return __uint_as_float(g << 16); }
__device__ inline float bfhi(unsigned g) { return __uint_as_float(g & 0xffff0000u); }

__device__ inline int get_ei(const int* ei, int is64, long idx) {
    return is64 ? ei[2 * idx] : ei[(int)idx];
}

// In-block int64 detection: OR of odd words of the first 2048 src entries
// (zero for little-endian int64 ids < 2^31; random node ids for int32).
__device__ inline int detect_is64(const int* __restrict__ ei, int tid) {
    __shared__ int dred[4];
    int v = 0;
    for (int i = tid; i < 2048; i += 256) v |= ei[2 * i + 1];
#pragma unroll
    for (int off = 32; off; off >>= 1) v |= __shfl_xor(v, off);
    if ((tid & 63) == 0) dred[tid >> 6] = v;
    __syncthreads();
    int r = dred[0] | dred[1] | dred[2] | dred[3];
    __syncthreads();   // protect dred reuse safety across callers
    return (r == 0) ? 1 : 0;
}

// ---------------------------------------------------------------------------
// Counting-sort CSR build.
// ---------------------------------------------------------------------------
__global__ __launch_bounds__(256) void p1_hist(const int* __restrict__ ei,
                                               int* __restrict__ HH,
                                               int E, int n, int nblk) {
    __shared__ int cnt[256];
    int tid = threadIdx.x;
    int is64 = detect_is64(ei, tid);
    int nbuk = (n + (1 << BUCKET_SHIFT) - 1) >> BUCKET_SHIFT;  // <=256
    for (int b = tid; b < nbuk; b += 256) cnt[b] = 0;
    __syncthreads();
    int total = E + n;
    int beg = blockIdx.x * CHUNK;
    int end = beg + CHUNK; if (end > total) end = total;
    for (int i = beg + tid; i < end; i += 256) {
        int d = (i < E) ? get_ei(ei, is64, (long)E + i) : (i - E);
        atomicAdd(&cnt[d >> BUCKET_SHIFT], 1);
    }
    __syncthreads();
    for (int b = tid; b < nbuk; b += 256) HH[b * nblk + blockIdx.x] = cnt[b];
}

__global__ __launch_bounds__(256) void scan1_kernel(const int* __restrict__ src,
                                                    int* __restrict__ bsums, int n) {
    int t = threadIdx.x;
    int i0 = blockIdx.x * SCAN_ELEMS + 4 * t;
    int4 v = make_int4(0, 0, 0, 0);
    if (i0 + 3 < n) v = *(const int4*)(src + i0);
    else {
        if (i0 + 0 < n) v.x = src[i0 + 0];
        if (i0 + 1 < n) v.y = src[i0 + 1];
        if (i0 + 2 < n) v.z = src[i0 + 2];
        if (i0 + 3 < n) v.w = src[i0 + 3];
    }
    int s = v.x + v.y + v.z + v.w;
#pragma unroll
    for (int off = 32; off; off >>= 1) s += __shfl_down(s, off);
    __shared__ int ws[4];
    if ((t & 63) == 0) ws[t >> 6] = s;
    __syncthreads();
    if (t == 0) bsums[blockIdx.x] = ws[0] + ws[1] + ws[2] + ws[3];
}

__global__ __launch_bounds__(256) void scan3g_kernel(const int* __restrict__ src,
                                                     const int* __restrict__ bsums,
                                                     int* __restrict__ out, int n, int nb) {
    int b = blockIdx.x;
    int t = threadIdx.x;
    __shared__ int sb[256];
    int bv = (t < nb) ? bsums[t] : 0;
    sb[t] = bv;
    __syncthreads();
    for (int off = 1; off < 256; off <<= 1) {
        int u = (t >= off) ? sb[t - off] : 0;
        __syncthreads();
        sb[t] += u;
        __syncthreads();
    }
    int blockbase = (b == 0) ? 0 : sb[b - 1];

    int i0 = b * SCAN_ELEMS + 4 * t;
    int4 v = make_int4(0, 0, 0, 0);
    if (i0 + 3 < n) v = *(const int4*)(src + i0);
    else {
        if (i0 + 0 < n) v.x = src[i0 + 0];
        if (i0 + 1 < n) v.y = src[i0 + 1];
        if (i0 + 2 < n) v.z = src[i0 + 2];
        if (i0 + 3 < n) v.w = src[i0 + 3];
    }
    int s0 = v.x, s1 = s0 + v.y, s2 = s1 + v.z, s3 = s2 + v.w;
    __shared__ int sh[256];
    sh[t] = s3;
    __syncthreads();
    for (int off = 1; off < 256; off <<= 1) {
        int u = (t >= off) ? sh[t - off] : 0;
        __syncthreads();
        sh[t] += u;
        __syncthreads();
    }
    int base = blockbase + sh[t] - s3;
    if (i0 + 0 < n) out[i0 + 0] = base;
    if (i0 + 1 < n) out[i0 + 1] = base + s0;
    if (i0 + 2 < n) out[i0 + 2] = base + s1;
    if (i0 + 3 < n) out[i0 + 3] = base + s2;
}

__global__ __launch_bounds__(256) void p3_scatter(const int* __restrict__ ei,
                                                  const int* __restrict__ scanHH,
                                                  int* __restrict__ sorted,
                                                  int E, int n, int nblk) {
    __shared__ int base[256];
    __shared__ int cur[256];
    int tid = threadIdx.x;
    int is64 = detect_is64(ei, tid);
    int nbuk = (n + (1 << BUCKET_SHIFT) - 1) >> BUCKET_SHIFT;
    for (int b = tid; b < nbuk; b += 256) {
        base[b] = scanHH[b * nblk + blockIdx.x];
        cur[b] = 0;
    }
    __syncthreads();
    int total = E + n;
    int beg = blockIdx.x * CHUNK;
    int end = beg + CHUNK; if (end > total) end = total;
    for (int i = beg + tid; i < end; i += 256) {
        int s, d;
        if (i < E) {
            s = get_ei(ei, is64, i);
            d = get_ei(ei, is64, (long)E + i);
        } else {
            s = d = i - E;
        }
        int b = d >> BUCKET_SHIFT;
        int p = base[b] + atomicAdd(&cur[b], 1);
        sorted[p] = (s << BUCKET_SHIFT) | (d & ((1 << BUCKET_SHIFT) - 1));
    }
}

__global__ __launch_bounds__(256) void p4_finalize(const int* __restrict__ scanHH,
                                                   const int* __restrict__ sorted,
                                                   int* __restrict__ ptr,
                                                   int* __restrict__ csr_src,
                                                   int n, int nblk, int T) {
    int b = blockIdx.x;
    int nbuk = gridDim.x;
    int tid = threadIdx.x;
    int node0 = b << BUCKET_SHIFT;
    int nn = n - node0; if (nn > (1 << BUCKET_SHIFT)) nn = 1 << BUCKET_SHIFT;
    int beg = scanHH[b * nblk];
    int end = (b + 1 < nbuk) ? scanHH[(b + 1) * nblk] : T;

    __shared__ int cnt[512];
    __shared__ int pair[256];
    __shared__ int exc[512];
    cnt[tid] = 0; cnt[tid + 256] = 0;
    __syncthreads();
    for (int j = beg + tid; j < end; j += 256) {
        int v = sorted[j];
        atomicAdd(&cnt[v & ((1 << BUCKET_SHIFT) - 1)], 1);
    }
    __syncthreads();
    int psum = cnt[2 * tid] + cnt[2 * tid + 1];
    pair[tid] = psum;
    __syncthreads();
    for (int off = 1; off < 256; off <<= 1) {
        int u = (tid >= off) ? pair[tid - off] : 0;
        __syncthreads();
        pair[tid] += u;
        __syncthreads();
    }
    int pexc = pair[tid] - psum;
    exc[2 * tid] = pexc;
    exc[2 * tid + 1] = pexc + cnt[2 * tid];
    __syncthreads();
    for (int i = tid; i < nn; i += 256) ptr[node0 + i] = beg + exc[i];
    if (node0 + nn == n && tid == 0) ptr[n] = T;
    cnt[tid] = exc[tid]; cnt[tid + 256] = exc[tid + 256];
    __syncthreads();
    for (int j = beg + tid; j < end; j += 256) {
        int v = sorted[j];
        int p = beg + atomicAdd(&cnt[v & ((1 << BUCKET_SHIFT) - 1)], 1);
        csr_src[p] = ((unsigned)v) >> BUCKET_SHIFT;
    }
}

// ---------------------------------------------------------------------------
// W pre-pack into MFMA B-fragment order (bf16). Unchanged.
// ---------------------------------------------------------------------------
__global__ __launch_bounds__(256) void pack_w(const float* __restrict__ W1,
                                              const float* __restrict__ W2,
                                              unsigned short* __restrict__ wp1,
                                              unsigned short* __restrict__ wp2) {
    int t = blockIdx.x * 256 + threadIdx.x;
    if (t >= 24 * 64) return;
    int f = t >> 6, l = t & 63;
    int lm = l & 15, lg = l >> 4;
    const float* W = (f < 16) ? W1 : W2;
    unsigned short* wp = (f < 16) ? wp1 : wp2;
    int idx = (f < 16) ? f : (f - 16);
    int kt = idx >> 2, ct = idx & 3;
    union { u16x8 v; unsigned short u[8]; } o;
#pragma unroll
    for (int e = 0; e < 8; ++e)
        o.u[e] = f2bf(W[(size_t)(32 * kt + 8 * lg + e) * 64 + 16 * ct + lm]);
    *(u16x8*)(wp + ((size_t)idx * 64 + l) * 8) = o.v;
}

// ---------------------------------------------------------------------------
// MFMA projection. XBF=false: x is fp32 rows of K floats (layer 1).
// XBF=true: x is bf16 rows of 64 (layer 2, fed directly from agg1's bf16 out).
// ---------------------------------------------------------------------------
#define MFMA_BF16(acc, a, b) \
    asm("s_nop 1\n\tv_mfma_f32_16x16x32_bf16 %0, %1, %2, %0" \
        : "+v"(acc) : "v"(a), "v"(b))

template <int KT, bool XBF>   // K = 32*KT
__global__ __launch_bounds__(256) void proj_mfma(const void* __restrict__ xin,
                                                 const unsigned short* __restrict__ Wp,
                                                 const float* __restrict__ att_s,
                                                 const float* __restrict__ att_d,
                                                 unsigned short* __restrict__ h2,
                                                 float* __restrict__ asrc,
                                                 float* __restrict__ adst, int n) {
    constexpr int K = 32 * KT;
    __shared__ alignas(16) unsigned short lb[4][16 * 72];
    int tid = threadIdx.x;
    int wid = tid >> 6, l = tid & 63;
    int lm = l & 15, lg = l >> 4;

    int node0 = blockIdx.x * 64 + wid * 16;
    if (node0 >= n) return;   // wave-uniform; kernel uses no block barriers

    float as_c[4], ad_c[4];
#pragma unroll
    for (int ct = 0; ct < 4; ++ct) {
        as_c[ct] = att_s[16 * ct + lm];
        ad_c[ct] = att_d[16 * ct + lm];
    }

    f32x4 acc[4] = {};

    int arow = node0 + lm;
    bool rowok = arow < n;

#pragma unroll
    for (int kt = 0; kt < KT; ++kt) {
        i32x4 af = {0, 0, 0, 0};
        if (XBF) {
            const unsigned short* xb = (const unsigned short*)xin
                                       + (size_t)arow * K + 32 * kt + 8 * lg;
            if (rowok) af = *(const i32x4*)xb;
        } else {
            const float* xp = (const float*)xin + (size_t)arow * K + 8 * lg + 32 * kt;
            float4 v0 = make_float4(0.f, 0.f, 0.f, 0.f);
            float4 v1 = v0;
            if (rowok) {
                v0 = *(const float4*)(xp);
                v1 = *(const float4*)(xp + 4);
            }
            af[0] = (int)((unsigned)f2bf(v0.x) | ((unsigned)f2bf(v0.y) << 16));
            af[1] = (int)((unsigned)f2bf(v0.z) | ((unsigned)f2bf(v0.w) << 16));
            af[2] = (int)((unsigned)f2bf(v1.x) | ((unsigned)f2bf(v1.y) << 16));
            af[3] = (int)((unsigned)f2bf(v1.z) | ((unsigned)f2bf(v1.w) << 16));
        }
#pragma unroll
        for (int ct = 0; ct < 4; ++ct) {
            i32x4 bf = *(const i32x4*)(Wp + (((kt * 4 + ct) * 64) + l) * 8);
            MFMA_BF16(acc[ct], af, bf);
        }
    }
    // MFMA-write -> VALU-read hazard fence, bound to the accumulators.
    asm volatile("s_nop 7\n\ts_nop 7"
                 : "+v"(acc[0]), "+v"(acc[1]), "+v"(acc[2]), "+v"(acc[3]));

    // attention dots: lane holds cols {16*ct+lm} of rows {4*lg+r}
    float ps[4], pd[4];
#pragma unroll
    for (int r = 0; r < 4; ++r) {
        float s = 0.f, d = 0.f;
#pragma unroll
        for (int ct = 0; ct < 4; ++ct) {
            s = fmaf(acc[ct][r], as_c[ct], s);
            d = fmaf(acc[ct][r], ad_c[ct], d);
        }
        ps[r] = s; pd[r] = d;
    }
#pragma unroll
    for (int off = 1; off < 16; off <<= 1) {
#pragma unroll
        for (int r = 0; r < 4; ++r) {
            ps[r] += __shfl_xor(ps[r], off);
            pd[r] += __shfl_xor(pd[r], off);
        }
    }
    if (lm == 0) {
#pragma unroll
        for (int r = 0; r < 4; ++r) {
            int node = node0 + 4 * lg + r;
            if (node < n) { asrc[node] = ps[r]; adst[node] = pd[r]; }
        }
    }

    // h2 repack via per-wave LDS buffer (wave-local sync only)
    unsigned short* wb = lb[wid];
#pragma unroll
    for (int ct = 0; ct < 4; ++ct)
#pragma unroll
        for (int r = 0; r < 4; ++r)
            wb[(4 * lg + r) * 72 + 16 * ct + lm] = f2bf(acc[ct][r]);
    asm volatile("s_waitcnt lgkmcnt(0)" ::: "memory");
    int ch = l & 7;                       // 16B chunk within a 128B row
#pragma unroll
    for (int p = 0; p < 2; ++p) {
        int rr = (l >> 3) + 8 * p;        // 8 rows per pass, 2 passes = 16 rows
        u16x8 ov = *(const u16x8*)(wb + rr * 72 + 8 * ch);
        int onode = node0 + rr;
        if (onode < n)
            *(u16x8*)(h2 + (size_t)onode * 64 + 8 * ch) = ov;
    }
}

// ---------------------------------------------------------------------------
// Fused edge softmax + aggregation. Slot/f decomposition (slot=lane>>4,
// f=lane&15); {src,w} packed int2 in per-wave LDS. Inner loop processes
// 16 edges/iter with FOUR independent h2 gathers in flight (the measured-best
// MLP from R2; R3's 2-deep variant cost +2.4us on both agg dispatches).
// OOB lanes in the fill phase write {0, 0.f} so pad slots do w=0 fma against
// the L1-hot row 0 -- no remainder handling in the gather loop.
// ---------------------------------------------------------------------------
template <bool FMEAN>
__global__ __launch_bounds__(256) void agg_kernel(const int* __restrict__ ptr,
                                                  const int* __restrict__ srcs,
                                                  const unsigned short* __restrict__ h2,
                                                  const float* __restrict__ asrc,
                                                  const float* __restrict__ adst,
                                                  const float* __restrict__ bias,
                                                  unsigned short* __restrict__ outbf,
                                                  float* __restrict__ partials,
                                                  int n, int do_relu) {
    __shared__ int2  sm[4][64];
    __shared__ float red[256];
    int tid = threadIdx.x;
    int lane = tid & 63, wid = tid >> 6;
    int slot = lane >> 4, f = lane & 15;
    const char* h2b = (const char*)h2;
    unsigned fo = (unsigned)f << 3;            // byte offset of uint2 in row
    float4 bv = *(const float4*)(bias + 4 * f);
    float ms0 = 0.f, ms1 = 0.f, ms2 = 0.f, ms3 = 0.f;

    int gwave = (blockIdx.x * blockDim.x + tid) >> 6;
    int nwaves = (gridDim.x * blockDim.x) >> 6;
    for (int node = gwave; node < n; node += nwaves) {
        int beg = ptr[node], end = ptr[node + 1];
        float ad = adst[node];
        float a0 = 0.f, a1 = 0.f, a2 = 0.f, a3 = 0.f, wsum = 0.f;
        for (int b = beg; b < end; b += 64) {
            int blen = end - b; if (blen > 64) blen = 64;
            int sv = 0; float wv = 0.f;
            if (lane < blen) {
                sv = srcs[b + lane];             // coalesced
                float e = asrc[sv] + ad;         // L2-resident 4B gather
                e = (e > 0.f) ? e : NEG_SLOPE * e;
                wv = __expf(e);
            }
            wsum += wv;
            sm[wid][lane] = make_int2(sv, __float_as_int(wv));
            int ni = (blen + 15) >> 4;           // 16 edges per iteration
            for (int j = 0; j < ni; ++j) {
                int2 swv[4];
#pragma unroll
                for (int u = 0; u < 4; ++u)
                    swv[u] = sm[wid][16 * j + 4 * u + slot];   // <=63, zero-pad
                uint2 g[4]; float w[4];
#pragma unroll
                for (int u = 0; u < 4; ++u) {
                    w[u] = __int_as_float(swv[u].y);
                    g[u] = *(const uint2*)(h2b + (((unsigned)swv[u].x << 7) + fo));
                }
#pragma unroll
                for (int u = 0; u < 4; ++u) {
                    a0 = fmaf(w[u], bflo(g[u].x), a0);
                    a1 = fmaf(w[u], bfhi(g[u].x), a1);
                    a2 = fmaf(w[u], bflo(g[u].y), a2);
                    a3 = fmaf(w[u], bfhi(g[u].y), a3);
                }
            }
        }
        // a-reduce across the 4 slots (lane bits 4,5); wsum over all 64 lanes
        a0 += __shfl_xor(a0, 16); a0 += __shfl_xor(a0, 32);
        a1 += __shfl_xor(a1, 16); a1 += __shfl_xor(a1, 32);
        a2 += __shfl_xor(a2, 16); a2 += __shfl_xor(a2, 32);
        a3 += __shfl_xor(a3, 16); a3 += __shfl_xor(a3, 32);
#pragma unroll
        for (int off = 32; off; off >>= 1) wsum += __shfl_xor(wsum, off);
        float inv = 1.f / (wsum + 1e-16f);
        float o0 = a0 * inv + bv.x;
        float o1 = a1 * inv + bv.y;
        float o2 = a2 * inv + bv.z;
        float o3 = a3 * inv + bv.w;
        if (!FMEAN) {
            if (do_relu) {
                o0 = fmaxf(o0, 0.f); o1 = fmaxf(o1, 0.f);
                o2 = fmaxf(o2, 0.f); o3 = fmaxf(o3, 0.f);
            }
            if (slot == 0) {
                u16x4 ov;
                ov[0] = f2bf(o0); ov[1] = f2bf(o1);
                ov[2] = f2bf(o2); ov[3] = f2bf(o3);
                *(u16x4*)(outbf + (size_t)node * 64 + 4 * f) = ov;
            }
        } else {
            if (slot == 0) { ms0 += o0; ms1 += o1; ms2 += o2; ms3 += o3; }
        }
    }
    if (FMEAN) {
        if (slot == 0)
            *(float4*)(red + wid * 64 + 4 * f) = make_float4(ms0, ms1, ms2, ms3);
        __syncthreads();
        if (tid < 64) {
            float t = red[tid] + red[64 + tid] + red[128 + tid] + red[192 + tid];
            partials[(size_t)blockIdx.x * 64 + tid] = t;
        }
    }
}

__global__ __launch_bounds__(256) void reduce_mean(const float* __restrict__ partials,
                                                   float* __restrict__ out,
                                                   int nb, float inv_n) {
    __shared__ float red[256];
    int f = threadIdx.x & 63;
    int w = threadIdx.x >> 6;
    int idx = blockIdx.x * 4 + w;
    int stride = gridDim.x * 4;
    float s = 0.f;
    for (int r = idx; r < nb; r += stride) s += partials[(size_t)r * 64 + f];
    red[threadIdx.x] = s;
    __syncthreads();
    if (w == 0) {
        float t = red[f] + red[64 + f] + red[128 + f] + red[192 + f];
        atomicAdd(&out[f], t * inv_n);
    }
}

extern "C" void kernel_launch(void* const* d_in, const int* in_sizes, int n_in,
                              void* d_out, int out_size, void* d_ws, size_t ws_size,
                              hipStream_t stream) {
    const float* x   = (const float*)d_in[0];
    const int*   ei  = (const int*)d_in[1];
    // d_in[2] = edge_attr (unused by reference, edge_dim=None)
    const float* W1  = (const float*)d_in[3];
    const float* as1 = (const float*)d_in[4];
    const float* ad1 = (const float*)d_in[5];
    const float* b1  = (const float*)d_in[6];
    const float* W2  = (const float*)d_in[7];
    const float* as2 = (const float*)d_in[8];
    const float* ad2 = (const float*)d_in[9];
    const float* b2  = (const float*)d_in[10];
    float* out = (float*)d_out;

    const int N = in_sizes[0] / 128;  // 100000
    const int E = in_sizes[1] / 2;    // 1600000
    const int T = E + N;              // edges incl. self-loops

    const int NBUK = (N + (1 << BUCKET_SHIFT) - 1) >> BUCKET_SHIFT;   // 196
    const int NBLK = (T + CHUNK - 1) / CHUNK;                          // 831
    const int NHH  = NBUK * NBLK;                                      // ~163k
    const int NBS  = (NHH + SCAN_ELEMS - 1) / SCAN_ELEMS;              // 160 (<=256)
    const int AGRID = (N + 3) / 4;    // one node per wave

    // Workspace carve-up (256B-aligned)
    size_t off = 0;
    char* base = (char*)d_ws;
    auto alloc = [&](size_t bytes) -> void* {
        void* p = base + off;
        off += (bytes + 255) & ~(size_t)255;
        return p;
    };
    int*   ptr     = (int*)alloc(((size_t)N + 1) * 4);
    int*   bsums   = (int*)alloc(256 * 4);
    int*   HH      = (int*)alloc((size_t)NHH * 4);
    int*   scanHH  = (int*)alloc((size_t)NHH * 4);
    int*   csr_src = (int*)alloc((size_t)T * 4);
    float* asrc    = (float*)alloc((size_t)N * 4);
    float* adst    = (float*)alloc((size_t)N * 4);
    unsigned short* h2 = (unsigned short*)alloc((size_t)N * 64 * 2);
    // bufB: bf16 h1 (N*64*2) + overlays (sorted T*4, partials AGRID*64*4)
    unsigned short* bufB = (unsigned short*)alloc((size_t)N * 64 * 4);
    unsigned short* wp1 = (unsigned short*)alloc(16 * 64 * 8 * 2);  // 16 KB
    unsigned short* wp2 = (unsigned short*)alloc(8 * 64 * 8 * 2);   //  8 KB
    int*   sorted  = (int*)bufB;      // overlay: dead before agg1 writes bufB
    float* partials = (float*)bufB;   // overlay: bufB dead after proj2 reads it
    (void)ws_size;

    // --- Weight pre-pack for MFMA B-fragments ---
    pack_w<<<6, 256, 0, stream>>>(W1, W2, wp1, wp2);

    // --- CSR build via counting sort (shared by both layers) ---
    p1_hist<<<NBLK, 256, 0, stream>>>(ei, HH, E, N, NBLK);
    scan1_kernel<<<NBS, 256, 0, stream>>>(HH, bsums, NHH);
    scan3g_kernel<<<NBS, 256, 0, stream>>>(HH, bsums, scanHH, NHH, NBS);
    p3_scatter<<<NBLK, 256, 0, stream>>>(ei, scanHH, sorted, E, N, NBLK);
    p4_finalize<<<NBUK, 256, 0, stream>>>(scanHH, sorted, ptr, csr_src, N, NBLK, T);

    const int PGRID = (N + 63) / 64;

    // --- Layer 1: MFMA proj (x @ W1) -> bf16 h2 + attention aggregate + ReLU ---
    proj_mfma<4, false><<<PGRID, 256, 0, stream>>>(x, wp1, as1, ad1, h2, asrc, adst, N);
    agg_kernel<false><<<AGRID, 256, 0, stream>>>(ptr, csr_src, h2, asrc, adst,
                                                 b1, bufB, nullptr, N, 1);

    // --- Layer 2: MFMA proj (h_bf16 @ W2) -> bf16 h2 + attention agg + mean ---
    proj_mfma<2, true><<<PGRID, 256, 0, stream>>>(bufB, wp2, as2, ad2, h2, asrc, adst, N);
    agg_kernel<true><<<AGRID, 256, 0, stream>>>(ptr, csr_src, h2, asrc, adst,
                                                b2, nullptr, partials, N, 0);
    hipMemsetAsync(out, 0, 64 * 4, stream);
    reduce_mean<<<64, 256, 0, stream>>>(partials, out, AGRID, 1.f / (float)N);
}